// Round 16
// baseline (13.295 us; speedup 1.0000x reference)
//
#include <hip/hip_runtime.h>
#include <math.h>

#define NPTS 8192
#define G 1024                      // CDF-equalized buckets (lambda ~ 8 each)
#define CAP 24                      // slots per bucket; P(Pois(8)>24)~2e-7
#define THREADS 1024
#define VPT (NPTS / THREADS)        // 8 candidates per thread
#define QPB 256                     // queries per block
#define NSLICE (NPTS / QPB)         // 32 slices per plane
#define NBLK (6 * NSLICE)           // 192 blocks
#define SPILL_CAP 1024

// Monotone CDF bucketing: equal expected occupancy for N(0,1) inputs.
// Exactness holds for ANY monotone bucket map; distribution only affects speed.
__device__ __forceinline__ int bucket_cdf(float v) {
    const float pc = 0.5f * (1.0f + erff(v * 0.70710678118f));
    const int g = (int)(pc * (float)G);
    return min(g, G - 1);
}

// Fused kernel: block = (plane p, slice s of 256 queries). Build = ONE atomic
// phase (atomicAdd on bucket count == cursor, direct slot write); overflow ->
// spill list scanned by every query. No histogram pre-pass, no prefix scan.
// Query: masked float4 scan of own bucket, then bucket-wise expansion with
// CONTENT-based stop bounds (vlo/vhi over scanned slot values): any unscanned
// value in a bucket < dl is < vlo; > dr is > vhi (monotone bucketing) -> stop
// when m <= min(x-vlo, vhi-x). Exact & deterministic for any atomic order.
__global__ __launch_bounds__(THREADS) void chamfer_fused_kernel(
    const float* __restrict__ pred, const float* __restrict__ target,
    float* __restrict__ partials)
{
    const int b = blockIdx.x;
    const int p = b >> 5, s = b & (NSLICE - 1);
    const int arr = p / 3, ch = p - arr * 3;
    const float* csrc = arr ? target : pred;   // candidates: this plane
    const float* qsrc = arr ? pred   : target; // queries: other array

    __shared__ unsigned cnt[G];                    // 4 KB counts/cursors
    __shared__ unsigned spillcnt;
    __shared__ float    spill[SPILL_CAP];          // 4 KB
    __shared__ __align__(16) float slots[G * CAP]; // 96 KB
    __shared__ float    wsum[THREADS / 64];

    const int t = threadIdx.x, lane = t & 63, wave = t >> 6;

    // Early independent loads.
    float x = 0.f;
    if (t < QPB) x = qsrc[(s * QPB + t) * 3 + ch];

    float v[VPT];
    #pragma unroll
    for (int j = 0; j < VPT; ++j)
        v[j] = csrc[(t + j * THREADS) * 3 + ch];

    cnt[t] = 0u;                                   // G == THREADS
    if (t == 0) spillcnt = 0u;
    __syncthreads();

    // Single-phase scatter: one atomic per candidate.
    #pragma unroll
    for (int j = 0; j < VPT; ++j) {
        const int g = bucket_cdf(v[j]);
        const unsigned pos = atomicAdd(&cnt[g], 1u);
        if (pos < CAP) {
            slots[g * CAP + pos] = v[j];
        } else {                                   // ~never (lambda=8, CAP=24)
            const unsigned sp = atomicAdd(&spillcnt, 1u);
            if (sp < SPILL_CAP) spill[sp] = v[j];
        }
    }
    __syncthreads();

    // ---- query (4 waves) ----
    float m = 0.f;                                 // non-query threads add 0
    if (t < QPB) {
        m = 3.0e38f;
        float vlo = 3.0e38f, vhi = -3.0e38f;

        // Spills cover every overflowed value regardless of bucket.
        const unsigned sc = min(spillcnt, (unsigned)SPILL_CAP);
        for (unsigned k = 0; k < sc; ++k)          // expected 0 iterations
            m = fminf(m, fabsf(x - spill[k]));

        const int bx = bucket_cdf(x);

        // Masked scan of one bucket's slots; track min/max slot VALUE for
        // the content-based stop bounds. Stale slots masked by idx < cnt.
        auto scan = [&](int g) {
            const unsigned c = min(cnt[g], (unsigned)CAP);
            const float4* s4 = (const float4*)(slots + g * CAP); // 96B-aligned
            const int nk = ((int)c + 3) >> 2;
            for (int k = 0; k < nk; ++k) {
                const float4 cv = s4[k];
                const unsigned i0 = 4u * (unsigned)k;
                const float a0 = (i0 + 0 < c) ? cv.x : 3.0e38f;
                const float a1 = (i0 + 1 < c) ? cv.y : 3.0e38f;
                const float a2 = (i0 + 2 < c) ? cv.z : 3.0e38f;
                const float a3 = (i0 + 3 < c) ? cv.w : 3.0e38f;
                m = fminf(m, fminf(fminf(fabsf(x - a0), fabsf(x - a1)),
                                   fminf(fabsf(x - a2), fabsf(x - a3))));
                vlo = fminf(vlo, fminf(fminf(a0, a1), fminf(a2, a3)));
                const float b0 = (i0 + 0 < c) ? cv.x : -3.0e38f;
                const float b1 = (i0 + 1 < c) ? cv.y : -3.0e38f;
                const float b2 = (i0 + 2 < c) ? cv.z : -3.0e38f;
                const float b3 = (i0 + 3 < c) ? cv.w : -3.0e38f;
                vhi = fmaxf(vhi, fmaxf(fmaxf(b0, b1), fmaxf(b2, b3)));
            }
        };

        int dl = bx, dr = bx;                      // scanned bucket range
        scan(bx);
        // unscanned-left u: u < vlo -> |x-u| > x-vlo; right: u > vhi.
        // Negative/invalid bounds just force further (conservative) expansion.
        float bl = (dl <= 0)     ? 3.0e38f : (x - vlo);
        float br = (dr >= G - 1) ? 3.0e38f : (vhi - x);

        while (m > fminf(bl, br)) {                // typically 0-2 iterations
            if (bl <= br) {
                --dl; scan(dl);
                bl = (dl <= 0)     ? 3.0e38f : (x - vlo);
            } else {
                ++dr; scan(dr);
                br = (dr >= G - 1) ? 3.0e38f : (vhi - x);
            }
        }
    }

    // block sum (fixed order -> deterministic), plain store
    float sum = m;
    #pragma unroll
    for (int off = 32; off > 0; off >>= 1)
        sum += __shfl_down(sum, off, 64);
    if (lane == 0) wsum[wave] = sum;
    __syncthreads();
    if (t == 0) {
        float tot = 0.f;
        #pragma unroll
        for (int w = 0; w < THREADS / 64; ++w) tot += wsum[w];
        partials[b] = tot;
    }
}

// Final: one wave sums the 192 block-partials -> out = sum / NPTS.
__global__ __launch_bounds__(64) void final_kernel(
    const float* __restrict__ partials, float* __restrict__ out)
{
    const int t = threadIdx.x;
    float sf = partials[t] + partials[t + 64] + partials[t + 128];
    #pragma unroll
    for (int off = 32; off > 0; off >>= 1)
        sf += __shfl_down(sf, off, 64);
    if (t == 0) out[0] = sf * (1.0f / NPTS);
}

extern "C" void kernel_launch(void* const* d_in, const int* in_sizes, int n_in,
                              void* d_out, int out_size, void* d_ws, size_t ws_size,
                              hipStream_t stream) {
    const float* pred   = (const float*)d_in[0];
    const float* target = (const float*)d_in[1];
    float* out = (float*)d_out;
    float* partials = (float*)d_ws;   // [NBLK]

    chamfer_fused_kernel<<<NBLK, THREADS, 0, stream>>>(pred, target, partials);
    final_kernel<<<1, 64, 0, stream>>>(partials, out);
}